// Round 11
// baseline (181.917 us; speedup 1.0000x reference)
//
#include <hip/hip_runtime.h>

// out[N,256] = concat( x[N,128] @ Wx[128,128] + bx,
//                      segsum(edge_attr by src)[N,32] @ We[32,128] + be )
//
// Pipeline:
//   binA:  bucket packed (edge_id<<7 | node&127) by src>>7 (128-node buckets)
//   fused: per bucket: CSR build in LDS (all waves) -> SPLIT:
//            waves 0-3: register gather (2 thr/node, 16 loads in flight)
//            waves 4-7: hx MFMA (x@Wx) -- overlaps gather latency
//          -> barrier -> all waves: he MFMA (agg@We).

#define BSHIFT    7
#define BSIZE     128
#define NBMAX     1024
#define SEG_CAP   3584    // pairs per bucket (mean ~2046, sigma ~45, +34 sigma)
#define POOL_SZ   3648
#define CHUNK_A   8192
#define SPILL_CAP 65536

typedef short bf16x8 __attribute__((ext_vector_type(8)));
typedef float f32x4  __attribute__((ext_vector_type(4)));

__device__ __forceinline__ unsigned short f2bf(float f) {
    union { float f; unsigned u; } c; c.f = f;
    unsigned u = c.u;
    u += 0x7FFF + ((u >> 16) & 1);          // round-to-nearest-even
    return (unsigned short)(u >> 16);
}

__device__ __forceinline__ void acc4(float4& a, const float4 v) {
    a.x += v.x; a.y += v.y; a.z += v.z; a.w += v.w;
}

// ---------- Pass A: bucket edges (packed 4B pairs) ----------
__global__ __launch_bounds__(512) void binA_kernel(
    const int* __restrict__ src, int E, int nb,
    unsigned* __restrict__ segs, int* __restrict__ gcnt,
    int2* __restrict__ spill, int* __restrict__ spillcnt)
{
    __shared__ unsigned pool[CHUNK_A];      // 32 KB
    __shared__ int hist[NBMAX];
    __shared__ int offs[NBMAX];
    __shared__ int lcur[NBMAX];
    __shared__ int gbase[NBMAX];
    __shared__ int gallow[NBMAX];
    __shared__ int wsum[8];

    int tid = threadIdx.x;
    int base = blockIdx.x * CHUNK_A;

    for (int i = tid; i < NBMAX; i += 512) hist[i] = 0;
    __syncthreads();

    // count pass; cache src values in registers for the place pass
    int srcv[CHUNK_A / 512];
    #pragma unroll
    for (int u = 0; u < CHUNK_A / 512; ++u) {
        int e = base + tid + u * 512;
        int s = (e < E) ? src[e] : -1;
        srcv[u] = s;
        if (s >= 0) atomicAdd(&hist[s >> BSHIFT], 1);
    }
    __syncthreads();

    // block exclusive scan: each thread owns buckets 2t, 2t+1
    {
        int t2 = tid * 2;
        int c0 = hist[t2], c1 = hist[t2 + 1];
        int s = c0 + c1;
        int lane = tid & 63, wid = tid >> 6;
        int ws = s;
        #pragma unroll
        for (int d = 1; d < 64; d <<= 1) {
            int t = __shfl_up(ws, d);
            if (lane >= d) ws += t;
        }
        if (lane == 63) wsum[wid] = ws;
        __syncthreads();
        int woff = 0;
        #pragma unroll
        for (int w = 0; w < 8; ++w) if (w < wid) woff += wsum[w];
        int ex = woff + ws - s;
        offs[t2] = ex;          lcur[t2] = ex;
        offs[t2 + 1] = ex + c0; lcur[t2 + 1] = ex + c0;
    }
    __syncthreads();

    // reserve global segment space
    {
        int t2 = tid * 2;
        #pragma unroll
        for (int u = 0; u < 2; ++u) {
            int b = t2 + u;
            if (b < nb) {
                int cnt = hist[b];
                int b0 = cnt ? atomicAdd(&gcnt[b], cnt) : 0;
                gbase[b] = b0;
                int allow = SEG_CAP - b0;
                if (allow < 0) allow = 0;
                if (allow > cnt) allow = cnt;
                gallow[b] = allow;
            }
        }
    }
    __syncthreads();

    // place packed pairs into LDS pool grouped by bucket (src from registers)
    #pragma unroll
    for (int u = 0; u < CHUNK_A / 512; ++u) {
        int s = srcv[u];
        if (s >= 0) {
            int e = base + tid + u * 512;
            int b = s >> BSHIFT;
            int p = atomicAdd(&lcur[b], 1);
            pool[p] = ((unsigned)e << BSHIFT) | (unsigned)(s & (BSIZE - 1));
        }
    }
    __syncthreads();

    // coalesced flush: wave w handles buckets w, w+8, ...
    int wid = tid >> 6, lane = tid & 63;
    for (int b = wid; b < nb; b += 8) {
        int cnt = hist[b];
        int off = offs[b];
        int allow = gallow[b];
        unsigned* dst = segs + (size_t)b * SEG_CAP + gbase[b];
        for (int i = lane; i < allow; i += 64)
            dst[i] = pool[off + i];
        int excess = cnt - allow;
        if (excess > 0) {                 // never in practice
            int sb;
            if (lane == 0) sb = atomicAdd(spillcnt, excess);
            sb = __shfl(sb, 0);
            for (int i = lane; i < excess; i += 64) {
                int sp = sb + i;
                if (sp < SPILL_CAP) {
                    unsigned pv = pool[off + allow + i];
                    spill[sp] = make_int2((int)(pv >> BSHIFT),
                                          (b << BSHIFT) | (int)(pv & (BSIZE - 1)));
                }
            }
        }
    }
}

// ---------- fused: CSR build + (gather || hx MFMA) + he MFMA ----------
__global__ __launch_bounds__(512, 4) void fused_kernel(
    const unsigned* __restrict__ segs, const int* __restrict__ gcnt,
    const int2* __restrict__ spill, const int* __restrict__ spillcnt,
    const float4* __restrict__ ea4, const float* __restrict__ x,
    const float* __restrict__ Wx, const float* __restrict__ bx,
    const float* __restrict__ We, const float* __restrict__ be,
    float* __restrict__ out, int N)
{
    __shared__ int counts[BSIZE];
    __shared__ int starts[BSIZE + 1];
    __shared__ int cursor[BSIZE];
    __shared__ unsigned spool[SEG_CAP]; // raw packed entries, 14.3 KB
    __shared__ int pool[POOL_SZ];       // grouped edge ids, 14.6 KB
    __shared__ char sAgg[BSIZE * 64];   // agg tile bf16 swizzled, 8 KB
    __shared__ char sWeT[128 * 64];     // We^T bf16 swizzled, 8 KB
    __shared__ char sWxT[128 * 256];    // Wx^T bf16 swizzled, 32 KB

    int tid = threadIdx.x;
    int b = blockIdx.x;
    int node0 = b << BSHIFT;
    int lane = tid & 63, w = tid >> 6;
    int col = lane & 15, m = lane >> 4;

    int segn = gcnt[b]; if (segn > SEG_CAP) segn = SEG_CAP;
    const unsigned* seg = segs + (size_t)b * SEG_CAP;
    int nsp = *spillcnt; if (nsp > SPILL_CAP) nsp = SPILL_CAP;

    if (tid < BSIZE) counts[tid] = 0;
    // stage weights + segment into LDS
    for (int i = tid; i < 128 * 128; i += 512) {
        int k = i >> 7, j = i & 127;
        *(unsigned short*)(sWxT + j * 256 + ((k * 2) ^ ((j & 7) << 4))) = f2bf(Wx[i]);
    }
    for (int i = tid; i < 32 * 128; i += 512) {
        int k = i >> 7, j = i & 127;
        *(unsigned short*)(sWeT + j * 64 + ((k * 2) ^ ((j & 3) << 4))) = f2bf(We[i]);
    }
    for (int i = tid; i < segn; i += 512) spool[i] = seg[i];
    float bxv[8], bev[8];
    #pragma unroll
    for (int ct = 0; ct < 8; ++ct) {
        bxv[ct] = bx[ct * 16 + col];
        bev[ct] = be[ct * 16 + col];
    }
    __syncthreads();

    // count (from LDS)
    for (int i = tid; i < segn; i += 512)
        atomicAdd(&counts[spool[i] & (BSIZE - 1)], 1);
    if (nsp)
        for (int i = tid; i < nsp; i += 512) {
            int2 p = spill[i];
            if ((p.y >> BSHIFT) == b) atomicAdd(&counts[p.y & (BSIZE - 1)], 1);
        }
    __syncthreads();

    // exclusive scan over 128 counters (wave 0, 2 per lane)
    if (tid < 64) {
        int c0 = counts[tid * 2], c1 = counts[tid * 2 + 1];
        int s = c0 + c1;
        int ws = s;
        #pragma unroll
        for (int d = 1; d < 64; d <<= 1) {
            int t = __shfl_up(ws, d);
            if (tid >= d) ws += t;
        }
        int ex = ws - s;
        starts[tid * 2] = ex;          cursor[tid * 2] = ex;
        starts[tid * 2 + 1] = ex + c0; cursor[tid * 2 + 1] = ex + c0;
        if (tid == 63) starts[BSIZE] = ws;
    }
    __syncthreads();

    // fill grouped edge-id pool (from LDS)
    for (int i = tid; i < segn; i += 512) {
        unsigned pe = spool[i];
        int pos = atomicAdd(&cursor[pe & (BSIZE - 1)], 1);
        if (pos < POOL_SZ) pool[pos] = (int)(pe >> BSHIFT);
    }
    if (nsp)
        for (int i = tid; i < nsp; i += 512) {
            int2 p = spill[i];
            if ((p.y >> BSHIFT) == b) {
                int pos = atomicAdd(&cursor[p.y & (BSIZE - 1)], 1);
                if (pos < POOL_SZ) pool[pos] = p.x;
            }
        }
    __syncthreads();

    int srow = node0 + (w << 4) + m * 4;    // he-store rows for this lane
    int lrow = (w << 4) + col;              // he A-frag row

    if (tid < 256) {
        // ---- gather: 2 threads/node, 4 quads each, 4-edge unroll
        //      => 16 independent 16B loads in flight per thread.
        int g = tid >> 1;                   // node 0..127
        int h = (tid & 1) * 4;              // quad base 0 or 4
        int node = node0 + g;
        float4 a0 = {0.f,0.f,0.f,0.f}, a1 = {0.f,0.f,0.f,0.f};
        float4 a2 = {0.f,0.f,0.f,0.f}, a3 = {0.f,0.f,0.f,0.f};
        float4 c0 = {0.f,0.f,0.f,0.f}, c1 = {0.f,0.f,0.f,0.f};
        float4 c2 = {0.f,0.f,0.f,0.f}, c3 = {0.f,0.f,0.f,0.f};
        if (node < N) {
            int p0 = starts[g], p1 = starts[g + 1];
            if (p1 > POOL_SZ) p1 = POOL_SZ;
            int p = p0;
            for (; p + 4 <= p1; p += 4) {
                const float4* r0 = ea4 + (size_t)pool[p]     * 8 + h;
                const float4* r1 = ea4 + (size_t)pool[p + 1] * 8 + h;
                const float4* r2 = ea4 + (size_t)pool[p + 2] * 8 + h;
                const float4* r3 = ea4 + (size_t)pool[p + 3] * 8 + h;
                float4 v00 = r0[0], v01 = r0[1], v02 = r0[2], v03 = r0[3];
                float4 v10 = r1[0], v11 = r1[1], v12 = r1[2], v13 = r1[3];
                float4 v20 = r2[0], v21 = r2[1], v22 = r2[2], v23 = r2[3];
                float4 v30 = r3[0], v31 = r3[1], v32 = r3[2], v33 = r3[3];
                acc4(a0, v00); acc4(a1, v01); acc4(a2, v02); acc4(a3, v03);
                acc4(c0, v10); acc4(c1, v11); acc4(c2, v12); acc4(c3, v13);
                acc4(a0, v20); acc4(a1, v21); acc4(a2, v22); acc4(a3, v23);
                acc4(c0, v30); acc4(c1, v31); acc4(c2, v32); acc4(c3, v33);
            }
            for (; p < p1; ++p) {
                const float4* r = ea4 + (size_t)pool[p] * 8 + h;
                acc4(a0, r[0]); acc4(a1, r[1]); acc4(a2, r[2]); acc4(a3, r[3]);
            }
            acc4(a0, c0); acc4(a1, c1); acc4(a2, c2); acc4(a3, c3);
        }
        // write 4 quads (32 B) into swizzled sAgg row g
        int swz = (g & 7) << 4;
        uint2 u0, u1, u2, u3;
        u0.x = (unsigned)f2bf(a0.x) | ((unsigned)f2bf(a0.y) << 16);
        u0.y = (unsigned)f2bf(a0.z) | ((unsigned)f2bf(a0.w) << 16);
        u1.x = (unsigned)f2bf(a1.x) | ((unsigned)f2bf(a1.y) << 16);
        u1.y = (unsigned)f2bf(a1.z) | ((unsigned)f2bf(a1.w) << 16);
        u2.x = (unsigned)f2bf(a2.x) | ((unsigned)f2bf(a2.y) << 16);
        u2.y = (unsigned)f2bf(a2.z) | ((unsigned)f2bf(a2.w) << 16);
        u3.x = (unsigned)f2bf(a3.x) | ((unsigned)f2bf(a3.y) << 16);
        u3.y = (unsigned)f2bf(a3.z) | ((unsigned)f2bf(a3.w) << 16);
        *(uint2*)(sAgg + ((g * 64 + (h + 0) * 8) ^ swz)) = u0;
        *(uint2*)(sAgg + ((g * 64 + (h + 1) * 8) ^ swz)) = u1;
        *(uint2*)(sAgg + ((g * 64 + (h + 2) * 8) ^ swz)) = u2;
        *(uint2*)(sAgg + ((g * 64 + (h + 3) * 8) ^ swz)) = u3;
    } else {
        // ---- hx GEMM: waves 4-7, two 16-row tiles each, overlaps gather.
        int tt2 = (w - 4) * 2;
        #pragma unroll
        for (int s = 0; s < 2; ++s) {
            int tt = tt2 + s;
            int grow = node0 + tt * 16 + col;
            bool rok = grow < N;
            const float* xr = x + (size_t)grow * 128 + m * 8;
            bf16x8 ax[4];
            #pragma unroll
            for (int kk = 0; kk < 4; ++kk) {
                float4 p0 = {0.f,0.f,0.f,0.f}, p1 = {0.f,0.f,0.f,0.f};
                if (rok) {
                    p0 = *(const float4*)(xr + kk * 32);
                    p1 = *(const float4*)(xr + kk * 32 + 4);
                }
                bf16x8 a;
                a[0] = (short)f2bf(p0.x); a[1] = (short)f2bf(p0.y);
                a[2] = (short)f2bf(p0.z); a[3] = (short)f2bf(p0.w);
                a[4] = (short)f2bf(p1.x); a[5] = (short)f2bf(p1.y);
                a[6] = (short)f2bf(p1.z); a[7] = (short)f2bf(p1.w);
                ax[kk] = a;
            }
            int str = node0 + tt * 16 + m * 4;
            #pragma unroll
            for (int half = 0; half < 2; ++half) {
                f32x4 acc[4];
                #pragma unroll
                for (int ct = 0; ct < 4; ++ct) {
                    int c8 = half * 4 + ct;
                    acc[ct] = (f32x4){bxv[c8], bxv[c8], bxv[c8], bxv[c8]};
                }
                #pragma unroll
                for (int ct = 0; ct < 4; ++ct) {
                    int c8 = half * 4 + ct;
                    const char* brow = sWxT + (c8 * 16 + col) * 256;
                    int swz = (col & 7) << 4;
                    #pragma unroll
                    for (int kk = 0; kk < 4; ++kk) {
                        bf16x8 bfrag = *(const bf16x8*)(brow + ((kk * 64 + m * 16) ^ swz));
                        acc[ct] = __builtin_amdgcn_mfma_f32_16x16x32_bf16(ax[kk], bfrag, acc[ct], 0, 0, 0);
                    }
                }
                #pragma unroll
                for (int r = 0; r < 4; ++r) {
                    if (str + r < N) {
                        float* orow = out + (size_t)(str + r) * 256 + col + half * 64;
                        #pragma unroll
                        for (int ct = 0; ct < 4; ++ct)
                            orow[ct * 16] = acc[ct][r];
                    }
                }
            }
        }
    }

    __syncthreads();    // sAgg complete

    // ---- he GEMM: all 8 waves, [128,32] @ We + be -> out[:,128:256]
    {
        bf16x8 aa = *(const bf16x8*)(sAgg + ((lrow * 64 + m * 16) ^ ((lrow & 7) << 4)));

        f32x4 acc[8];
        #pragma unroll
        for (int ct = 0; ct < 8; ++ct)
            acc[ct] = (f32x4){bev[ct], bev[ct], bev[ct], bev[ct]};
        #pragma unroll
        for (int ct = 0; ct < 8; ++ct) {
            bf16x8 bwe = *(const bf16x8*)(sWeT + (ct * 16 + col) * 64 + ((m * 16) ^ ((col & 3) << 4)));
            acc[ct] = __builtin_amdgcn_mfma_f32_16x16x32_bf16(aa, bwe, acc[ct], 0, 0, 0);
        }

        #pragma unroll
        for (int r = 0; r < 4; ++r) {
            if (srow + r < N) {
                float* orow = out + (size_t)(srow + r) * 256 + 128 + col;
                #pragma unroll
                for (int ct = 0; ct < 8; ++ct)
                    orow[ct * 16] = acc[ct][r];
            }
        }
    }
}

// ---------- fallback: atomic scatter + convert + full GEMM ----------
__global__ __launch_bounds__(256) void scatter_kernel(
    const float4* __restrict__ ea4, const int* __restrict__ src,
    float* __restrict__ agg, int nquads)
{
    int t = blockIdx.x * blockDim.x + threadIdx.x;
    if (t >= nquads) return;
    int e = t >> 3, q = t & 7;
    float4 v = ea4[t];
    int node = src[e];
    float* dst = agg + (size_t)node * 32 + q * 4;
    atomicAdd(dst + 0, v.x); atomicAdd(dst + 1, v.y);
    atomicAdd(dst + 2, v.z); atomicAdd(dst + 3, v.w);
}

__global__ __launch_bounds__(256) void cvt_kernel(
    const float* __restrict__ agg, unsigned short* __restrict__ aggbf, int n)
{
    int t = blockIdx.x * blockDim.x + threadIdx.x;
    if (t < n) aggbf[t] = f2bf(agg[t]);
}

__global__ __launch_bounds__(512, 4) void mfma_gemm_full(
    const float* __restrict__ x, const unsigned short* __restrict__ aggbf,
    const float* __restrict__ Wx, const float* __restrict__ bx,
    const float* __restrict__ We, const float* __restrict__ be,
    float* __restrict__ out, int N, int ntiles)
{
    __shared__ char sWxT[128 * 256];
    __shared__ char sWeT[128 * 64];
    __shared__ char sX[128 * 256];
    __shared__ char sA[128 * 64];

    int tid = threadIdx.x;
    int lane = tid & 63, w = tid >> 6;
    int col = lane & 15, m = lane >> 4;

    for (int i = tid; i < 128 * 128; i += 512) {
        int k = i >> 7, j = i & 127;
        *(unsigned short*)(sWxT + j * 256 + ((k * 2) ^ ((j & 7) << 4))) = f2bf(Wx[i]);
    }
    for (int i = tid; i < 32 * 128; i += 512) {
        int k = i >> 7, j = i & 127;
        *(unsigned short*)(sWeT + j * 64 + ((k * 2) ^ ((j & 3) << 4))) = f2bf(We[i]);
    }
    float bxv[8], bev[8];
    #pragma unroll
    for (int ct = 0; ct < 8; ++ct) {
        bxv[ct] = bx[ct * 16 + col];
        bev[ct] = be[ct * 16 + col];
    }

    int lrow = (w << 4) + col;
    int swzA = (lrow & 7) << 4;

    for (int t = blockIdx.x; t < ntiles; t += gridDim.x) {
        int rbase_t = t << 7;
        __syncthreads();

        for (int i = tid; i < 128 * 32; i += 512) {
            int row = i >> 5, c4 = i & 31;
            int gr = rbase_t + row;
            float4 v = {0.f, 0.f, 0.f, 0.f};
            if (gr < N) v = *(const float4*)(x + (size_t)gr * 128 + c4 * 4);
            uint2 uu;
            uu.x = (unsigned)f2bf(v.x) | ((unsigned)f2bf(v.y) << 16);
            uu.y = (unsigned)f2bf(v.z) | ((unsigned)f2bf(v.w) << 16);
            *(uint2*)(sX + ((row * 256 + c4 * 8) ^ ((row & 7) << 4))) = uu;
        }
        {
            int row = tid >> 2, mm = tid & 3;
            int gr = rbase_t + row;
            bf16x8 av = {0, 0, 0, 0, 0, 0, 0, 0};
            if (gr < N) av = *(const bf16x8*)(aggbf + (size_t)gr * 32 + mm * 8);
            *(bf16x8*)(sA + ((row * 64 + mm * 16) ^ ((row & 7) << 4))) = av;
        }
        __syncthreads();

        bf16x8 ax[4];
        #pragma unroll
        for (int kk = 0; kk < 4; ++kk)
            ax[kk] = *(const bf16x8*)(sX + lrow * 256 + ((kk * 64 + m * 16) ^ swzA));
        bf16x8 aa = *(const bf16x8*)(sA + ((lrow * 64 + m * 16) ^ swzA));

        int srow = rbase_t + (w << 4) + m * 4;

        #pragma unroll
        for (int half = 0; half < 2; ++half) {
            f32x4 acc[8];
            #pragma unroll
            for (int ct = 0; ct < 4; ++ct) {
                int c8 = half * 4 + ct;
                acc[ct]     = (f32x4){bxv[c8], bxv[c8], bxv[c8], bxv[c8]};
                acc[4 + ct] = (f32x4){bev[c8], bev[c8], bev[c8], bev[c8]};
            }
            #pragma unroll
            for (int ct = 0; ct < 4; ++ct) {
                int c8 = half * 4 + ct;
                const char* brow = sWxT + (c8 * 16 + col) * 256;
                int swz = (col & 7) << 4;
                #pragma unroll
                for (int kk = 0; kk < 4; ++kk) {
                    bf16x8 bfrag = *(const bf16x8*)(brow + ((kk * 64 + m * 16) ^ swz));
                    acc[ct] = __builtin_amdgcn_mfma_f32_16x16x32_bf16(ax[kk], bfrag, acc[ct], 0, 0, 0);
                }
                bf16x8 bwe = *(const bf16x8*)(sWeT + (c8 * 16 + col) * 64 + ((m * 16) ^ ((col & 3) << 4)));
                acc[4 + ct] = __builtin_amdgcn_mfma_f32_16x16x32_bf16(aa, bwe, acc[4 + ct], 0, 0, 0);
            }
            #pragma unroll
            for (int r = 0; r < 4; ++r) {
                if (srow + r < N) {
                    float* orow = out + (size_t)(srow + r) * 256 + col + half * 64;
                    #pragma unroll
                    for (int ct = 0; ct < 4; ++ct) {
                        orow[ct * 16]       = acc[ct][r];
                        orow[128 + ct * 16] = acc[4 + ct][r];
                    }
                }
            }
        }
    }
}

extern "C" void kernel_launch(void* const* d_in, const int* in_sizes, int n_in,
                              void* d_out, int out_size, void* d_ws, size_t ws_size,
                              hipStream_t stream) {
    const float* x          = (const float*)d_in[0];
    const int*   edge_index = (const int*)d_in[1];   // [2,E] flat; row 0 = src
    const float* edge_attr  = (const float*)d_in[2];
    const float* Wx         = (const float*)d_in[3];
    const float* bx         = (const float*)d_in[4];
    const float* We         = (const float*)d_in[5];
    const float* be         = (const float*)d_in[6];
    float* out = (float*)d_out;

    int N = in_sizes[0] / 128;
    int E = in_sizes[2] / 32;
    int nb = (N + BSIZE - 1) >> BSHIFT;
    int ntiles = (N + 127) >> 7;

    char* ws = (char*)d_ws;
    size_t aggbfBytes = ((size_t)N * 32 * 2 + 255) & ~255ull;
    size_t segsBytes  = ((size_t)nb * SEG_CAP * 4 + 255) & ~255ull;
    size_t gcntBytes  = ((size_t)(nb + 1) * 4 + 255) & ~255ull;
    size_t spillBytes = (size_t)SPILL_CAP * 8;
    size_t need = aggbfBytes + segsBytes + gcntBytes + spillBytes;

    unsigned short* aggbf = (unsigned short*)ws;

    if (ws_size >= need && nb <= NBMAX) {
        unsigned* segs  = (unsigned*)(ws + aggbfBytes);
        int* gcnt       = (int*)(ws + aggbfBytes + segsBytes);
        int* spillcnt   = gcnt + nb;
        int2* spill     = (int2*)(ws + aggbfBytes + segsBytes + gcntBytes);

        hipMemsetAsync(gcnt, 0, (size_t)(nb + 1) * 4, stream);
        int nblkA = (E + CHUNK_A - 1) / CHUNK_A;
        binA_kernel<<<nblkA, 512, 0, stream>>>(edge_index, E, nb, segs, gcnt, spill, spillcnt);
        fused_kernel<<<nb, 512, 0, stream>>>(segs, gcnt, spill, spillcnt,
                                             (const float4*)edge_attr, x,
                                             Wx, bx, We, be, out, N);
    } else {
        float* aggf = (float*)(ws + aggbfBytes);
        hipMemsetAsync(aggf, 0, (size_t)N * 32 * 4, stream);
        int nq = E * 8;
        scatter_kernel<<<(nq + 255) / 256, 256, 0, stream>>>(
            (const float4*)edge_attr, edge_index, aggf, nq);
        cvt_kernel<<<(N * 32 + 255) / 256, 256, 0, stream>>>(aggf, aggbf, N * 32);
        int g = ntiles < 512 ? ntiles : 512;
        mfma_gemm_full<<<g, 512, 0, stream>>>(x, aggbf, Wx, bx, We, be, out, N, ntiles);
    }
}